// Round 1
// baseline (76.591 us; speedup 1.0000x reference)
//
#include <hip/hip_runtime.h>
#include <math.h>

#define B_N 4096
#define L_N 16
#define IT  256          // i-tile per block == blockDim
#define JT  128          // j sub-tile staged in LDS

#define LOG2E_F   1.4426950408889634f
#define LN2_F     0.6931471805599453f
#define LOG_2PI_F 1.8378770664093453f
#define NEG_BIG   (-1.0e30f)

// ws layout (floats):
//   partials: [njc][18][B_N]   field 0..15 = per-l exp2 sums, 16 = m2, 17 = sum2
//   bpart:    [16]             per-block sums from reduce kernel

extern "C" __global__ __launch_bounds__(256)
void btc_main(const float* __restrict__ z, const float* __restrict__ zm,
              const float* __restrict__ zlv, float* __restrict__ part,
              int jc /* j's per chunk (multiple of JT) */) {
    __shared__ float sMn[JT * L_N];
    __shared__ float sA [JT * L_N];
    __shared__ float sC [JT * L_N];

    const int tid = threadIdx.x;
    const int i   = blockIdx.x * IT + tid;
    const int jb  = blockIdx.y * jc;
    const int jend = jb + jc;

    // hoist z row into registers
    float zf[L_N];
    {
        const float4* z4 = (const float4*)(z + (size_t)i * L_N);
        #pragma unroll
        for (int q = 0; q < 4; ++q) {
            float4 v = z4[q];
            zf[4*q+0] = v.x; zf[4*q+1] = v.y; zf[4*q+2] = v.z; zf[4*q+3] = v.w;
        }
    }

    float accl[L_N];
    #pragma unroll
    for (int l = 0; l < L_N; ++l) accl[l] = 0.0f;
    float m2 = NEG_BIG, sum2 = 0.0f;

    for (int j0 = jb; j0 < jend; j0 += JT) {
        __syncthreads();   // protect previous tile's reads
        // stage + transform tile: JT*16 = 2048 elems, 8 per thread, coalesced
        for (int e = tid; e < JT * L_N; e += IT) {
            float mv = zm [(size_t)j0 * L_N + e];
            float lv = zlv[(size_t)j0 * L_N + e];
            sMn[e] = mv;
            sA[e]  = -0.5f * LOG2E_F * __builtin_amdgcn_exp2f(-lv * LOG2E_F);
            sC[e]  = -0.5f * LOG2E_F * (lv + LOG_2PI_F);
        }
        __syncthreads();

        for (int jj = 0; jj < JT; ++jj) {
            const float4* pM = (const float4*)&sMn[jj * L_N];
            const float4* pA = (const float4*)&sA [jj * L_N];
            const float4* pC = (const float4*)&sC [jj * L_N];
            float s2 = 0.0f;
            #pragma unroll
            for (int q = 0; q < 4; ++q) {
                float4 M4 = pM[q], A4 = pA[q], C4 = pC[q];
                float d0 = zf[4*q+0] - M4.x;
                float d1 = zf[4*q+1] - M4.y;
                float d2 = zf[4*q+2] - M4.z;
                float d3 = zf[4*q+3] - M4.w;
                float l0 = fmaf(d0*d0, A4.x, C4.x);
                float l1 = fmaf(d1*d1, A4.y, C4.y);
                float l2 = fmaf(d2*d2, A4.z, C4.z);
                float l3 = fmaf(d3*d3, A4.w, C4.w);
                s2 += l0; s2 += l1; s2 += l2; s2 += l3;
                accl[4*q+0] += __builtin_amdgcn_exp2f(l0);
                accl[4*q+1] += __builtin_amdgcn_exp2f(l1);
                accl[4*q+2] += __builtin_amdgcn_exp2f(l2);
                accl[4*q+3] += __builtin_amdgcn_exp2f(l3);
            }
            // online logsumexp (log2 domain) over j for the l-summed path
            float mnew = fmaxf(m2, s2);
            sum2 = fmaf(sum2, __builtin_amdgcn_exp2f(m2 - mnew),
                        __builtin_amdgcn_exp2f(s2 - mnew));
            m2 = mnew;
        }
    }

    float* base = part + (size_t)blockIdx.y * 18 * B_N + i;
    #pragma unroll
    for (int l = 0; l < L_N; ++l) base[(size_t)l * B_N] = accl[l];
    base[(size_t)16 * B_N] = m2;
    base[(size_t)17 * B_N] = sum2;
}

extern "C" __global__ __launch_bounds__(256)
void btc_reduce(const float* __restrict__ part, float* __restrict__ bpart, int njc) {
    const int tid = threadIdx.x;
    const int i   = blockIdx.x * 256 + tid;

    float accl[L_N];
    #pragma unroll
    for (int l = 0; l < L_N; ++l) accl[l] = 0.0f;
    float m2 = NEG_BIG, sum2 = 0.0f;

    for (int c = 0; c < njc; ++c) {
        const float* b = part + (size_t)c * 18 * B_N + i;
        #pragma unroll
        for (int l = 0; l < L_N; ++l) accl[l] += b[(size_t)l * B_N];
        float mc = b[(size_t)16 * B_N];
        float sc = b[(size_t)17 * B_N];
        float mnew = fmaxf(m2, mc);
        sum2 = fmaf(sum2, __builtin_amdgcn_exp2f(m2 - mnew),
                    sc * __builtin_amdgcn_exp2f(mc - mnew));
        m2 = mnew;
    }

    // log_qz_product (natural) = ln2 * sum_l log2(accl[l])
    float lqprod2 = 0.0f;
    #pragma unroll
    for (int l = 0; l < L_N; ++l) lqprod2 += __builtin_amdgcn_logf(accl[l]);
    // log_qz (natural) = ln2 * (m2 + log2(sum2))
    float lqz2 = m2 + __builtin_amdgcn_logf(sum2);
    float v = LN2_F * (lqz2 - lqprod2);

    // block reduction
    #pragma unroll
    for (int off = 32; off > 0; off >>= 1) v += __shfl_down(v, off);
    __shared__ float red[4];
    const int lane = tid & 63, w = tid >> 6;
    if (lane == 0) red[w] = v;
    __syncthreads();
    if (tid == 0) bpart[blockIdx.x] = red[0] + red[1] + red[2] + red[3];
}

extern "C" __global__ __launch_bounds__(64)
void btc_final(const float* __restrict__ bpart, float* __restrict__ out, int nb) {
    float v = (threadIdx.x < nb) ? bpart[threadIdx.x] : 0.0f;
    #pragma unroll
    for (int off = 32; off > 0; off >>= 1) v += __shfl_down(v, off);
    if (threadIdx.x == 0) {
        // (W_TC - 1.0) = 1.0 ; mean over B
        out[0] = v * (1.0f / (float)B_N);
    }
}

extern "C" void kernel_launch(void* const* d_in, const int* in_sizes, int n_in,
                              void* d_out, int out_size, void* d_ws, size_t ws_size,
                              hipStream_t stream) {
    const float* z   = (const float*)d_in[0];
    const float* zm  = (const float*)d_in[1];
    const float* zlv = (const float*)d_in[2];
    float* out = (float*)d_out;
    float* ws  = (float*)d_ws;

    int njc = 32;
    while (njc > 1) {
        size_t need = ((size_t)njc * 18 * B_N + 64) * sizeof(float);
        if (need <= ws_size) break;
        njc >>= 1;
    }
    const int jc = B_N / njc;   // multiple of JT for njc <= 32

    dim3 grid(B_N / IT, njc);
    hipLaunchKernelGGL(btc_main, grid, dim3(IT), 0, stream, z, zm, zlv, ws, jc);

    float* bpart = ws + (size_t)njc * 18 * B_N;
    hipLaunchKernelGGL(btc_reduce, dim3(B_N / 256), dim3(256), 0, stream, ws, bpart, njc);
    hipLaunchKernelGGL(btc_final, dim3(1), dim3(64), 0, stream, bpart, out, 16);
}

// Round 2
// 72.846 us; speedup vs baseline: 1.0514x; 1.0514x over previous
//
#include <hip/hip_runtime.h>
#include <math.h>

#define B_N 4096
#define L_N 16
#define NJC 32            // default j-chunks (grid.y)
#define ITI 64            // i's per block (one wave-width)
#define NW  4             // waves per block
#define JSTAGE 64         // j's staged per LDS tile
#define JPW (JSTAGE/NW)   // 16 j's per wave per tile

#define NHALF_LOG2E 0.7213475204444817f   // 0.5 * log2(e)
#define LOG2E_F     1.4426950408889634f
#define LN2_F       0.6931471805599453f
#define LOG_2PI_F   1.8378770664093453f

// LDS: staging arrays sA/sB/sC (12 KB) aliased with the cross-wave
// reduction buffer red[NW][17][ITI] (17408 B). Total 17408 B -> 8 blocks/CU
// (thread cap 2048/CU) -> 8 waves/SIMD.
#define LDS_BYTES (NW * 17 * ITI * 4)

extern "C" __global__ __launch_bounds__(256, 8)
void btc_main(const float* __restrict__ z, const float* __restrict__ zm,
              const float* __restrict__ zlv, float* __restrict__ part,
              int jc /* j's per chunk, multiple of JSTAGE */) {
    __shared__ __align__(16) char lds_raw[LDS_BYTES];
    float* sA = (float*)lds_raw;                 // [JSTAGE*L_N]
    float* sB = sA + JSTAGE * L_N;
    float* sC = sB + JSTAGE * L_N;
    float (*red)[17][ITI] = (float (*)[17][ITI])lds_raw;

    const int tid  = threadIdx.x;
    const int lane = tid & 63;
    const int w    = tid >> 6;
    const int i    = blockIdx.x * ITI + lane;
    const int jb   = blockIdx.y * jc;

    // hoist z row (same rows for all 4 waves; L1 serves it)
    float zf[L_N];
    {
        const float4* z4 = (const float4*)(z + (size_t)i * L_N);
        #pragma unroll
        for (int q = 0; q < 4; ++q) {
            float4 v = z4[q];
            zf[4*q+0] = v.x; zf[4*q+1] = v.y; zf[4*q+2] = v.z; zf[4*q+3] = v.w;
        }
    }

    float accl[L_N];
    #pragma unroll
    for (int l = 0; l < L_N; ++l) accl[l] = 0.0f;
    float sum2 = 0.0f;   // sum_j exp2( sum_l log2-density )  (no max needed: diag term >= ~2^-33)

    for (int t = 0; t < jc / JSTAGE; ++t) {
        __syncthreads();   // protect previous tile (and first-iter nothing)
        const int j0 = jb + t * JSTAGE;
        {
            // stage+transform: 1024 elems = exactly one float4 per thread
            const int e4 = tid * 4;
            float4 m4 = *(const float4*)(zm  + (size_t)j0 * L_N + e4);
            float4 v4 = *(const float4*)(zlv + (size_t)j0 * L_N + e4);
            float4 a4, b4, c4;
            {
                float A;
                A = -NHALF_LOG2E * __builtin_amdgcn_exp2f(-LOG2E_F * v4.x);
                a4.x = A; b4.x = -2.0f * A * m4.x;
                c4.x = fmaf(A, m4.x * m4.x, -NHALF_LOG2E * (v4.x + LOG_2PI_F));
                A = -NHALF_LOG2E * __builtin_amdgcn_exp2f(-LOG2E_F * v4.y);
                a4.y = A; b4.y = -2.0f * A * m4.y;
                c4.y = fmaf(A, m4.y * m4.y, -NHALF_LOG2E * (v4.y + LOG_2PI_F));
                A = -NHALF_LOG2E * __builtin_amdgcn_exp2f(-LOG2E_F * v4.z);
                a4.z = A; b4.z = -2.0f * A * m4.z;
                c4.z = fmaf(A, m4.z * m4.z, -NHALF_LOG2E * (v4.z + LOG_2PI_F));
                A = -NHALF_LOG2E * __builtin_amdgcn_exp2f(-LOG2E_F * v4.w);
                a4.w = A; b4.w = -2.0f * A * m4.w;
                c4.w = fmaf(A, m4.w * m4.w, -NHALF_LOG2E * (v4.w + LOG_2PI_F));
            }
            *(float4*)&sA[e4] = a4;
            *(float4*)&sB[e4] = b4;
            *(float4*)&sC[e4] = c4;
        }
        __syncthreads();

        const int jbase = w * JPW;
        for (int jj = 0; jj < JPW; ++jj) {
            const int jo = (jbase + jj) * L_N;
            const float4* pA = (const float4*)&sA[jo];
            const float4* pB = (const float4*)&sB[jo];
            const float4* pC = (const float4*)&sC[jo];
            float s2 = 0.0f;
            #pragma unroll
            for (int q = 0; q < 4; ++q) {
                float4 A4 = pA[q], B4 = pB[q], C4 = pC[q];
                float l0 = fmaf(fmaf(A4.x, zf[4*q+0], B4.x), zf[4*q+0], C4.x);
                float l1 = fmaf(fmaf(A4.y, zf[4*q+1], B4.y), zf[4*q+1], C4.y);
                float l2 = fmaf(fmaf(A4.z, zf[4*q+2], B4.z), zf[4*q+2], C4.z);
                float l3 = fmaf(fmaf(A4.w, zf[4*q+3], B4.w), zf[4*q+3], C4.w);
                s2 += (l0 + l1) + (l2 + l3);
                accl[4*q+0] += __builtin_amdgcn_exp2f(l0);
                accl[4*q+1] += __builtin_amdgcn_exp2f(l1);
                accl[4*q+2] += __builtin_amdgcn_exp2f(l2);
                accl[4*q+3] += __builtin_amdgcn_exp2f(l3);
            }
            sum2 += __builtin_amdgcn_exp2f(s2);
        }
    }

    // cross-wave combine (red aliases the staging arrays)
    __syncthreads();
    #pragma unroll
    for (int f = 0; f < L_N; ++f) red[w][f][lane] = accl[f];
    red[w][16][lane] = sum2;
    __syncthreads();
    if (w == 0) {
        float* base = part + (size_t)blockIdx.y * 17 * B_N + blockIdx.x * ITI + lane;
        #pragma unroll
        for (int f = 0; f < 17; ++f) {
            float v = (red[0][f][lane] + red[1][f][lane]) +
                      (red[2][f][lane] + red[3][f][lane]);
            base[(size_t)f * B_N] = v;
        }
    }
}

extern "C" __global__ __launch_bounds__(256)
void btc_reduce(const float* __restrict__ part, float* __restrict__ bpart, int njc) {
    const int tid = threadIdx.x;
    const int i   = blockIdx.x * 256 + tid;

    float accl[L_N];
    #pragma unroll
    for (int l = 0; l < L_N; ++l) accl[l] = 0.0f;
    float sum2 = 0.0f;

    for (int c = 0; c < njc; ++c) {
        const float* b = part + (size_t)c * 17 * B_N + i;
        #pragma unroll
        for (int l = 0; l < L_N; ++l) accl[l] += b[(size_t)l * B_N];
        sum2 += b[(size_t)16 * B_N];
    }

    // natural-log result = ln2 * (log2(sum2) - sum_l log2(accl[l]))
    float lqprod2 = 0.0f;
    #pragma unroll
    for (int l = 0; l < L_N; ++l) lqprod2 += __builtin_amdgcn_logf(accl[l]);
    float lqz2 = __builtin_amdgcn_logf(sum2);
    float v = LN2_F * (lqz2 - lqprod2);

    #pragma unroll
    for (int off = 32; off > 0; off >>= 1) v += __shfl_down(v, off);
    __shared__ float red[4];
    const int lane = tid & 63, w = tid >> 6;
    if (lane == 0) red[w] = v;
    __syncthreads();
    if (tid == 0) bpart[blockIdx.x] = red[0] + red[1] + red[2] + red[3];
}

extern "C" __global__ __launch_bounds__(64)
void btc_final(const float* __restrict__ bpart, float* __restrict__ out, int nb) {
    float v = (threadIdx.x < nb) ? bpart[threadIdx.x] : 0.0f;
    #pragma unroll
    for (int off = 32; off > 0; off >>= 1) v += __shfl_down(v, off);
    if (threadIdx.x == 0) {
        out[0] = v * (1.0f / (float)B_N);   // (W_TC - 1) = 1; mean over B
    }
}

extern "C" void kernel_launch(void* const* d_in, const int* in_sizes, int n_in,
                              void* d_out, int out_size, void* d_ws, size_t ws_size,
                              hipStream_t stream) {
    const float* z   = (const float*)d_in[0];
    const float* zm  = (const float*)d_in[1];
    const float* zlv = (const float*)d_in[2];
    float* out = (float*)d_out;
    float* ws  = (float*)d_ws;

    int njc = NJC;
    while (njc > 1) {
        size_t need = ((size_t)njc * 17 * B_N + 64) * sizeof(float);
        if (need <= ws_size) break;
        njc >>= 1;
    }
    const int jc = B_N / njc;   // multiple of JSTAGE for njc <= 64

    dim3 grid(B_N / ITI, njc);
    hipLaunchKernelGGL(btc_main, grid, dim3(ITI * NW), 0, stream, z, zm, zlv, ws, jc);

    float* bpart = ws + (size_t)njc * 17 * B_N;
    hipLaunchKernelGGL(btc_reduce, dim3(B_N / 256), dim3(256), 0, stream, ws, bpart, njc);
    hipLaunchKernelGGL(btc_final, dim3(1), dim3(64), 0, stream, bpart, out, 16);
}